// Round 2
// baseline (404.834 us; speedup 1.0000x reference)
//
#include <hip/hip_runtime.h>
#include <math.h>

#define NPTS 200000
#define KNBR 16
#define CDIM 32
#define TEMP 0.1f
#define WEIGHT 0.1f
#define EPSV 1e-8f

// One wave (64 lanes) handles 4 consecutive points = 64 neighbor rows.
// Gather load j (j=0..7): lane L reads row 8j + (L>>3), 16B chunk (L&7).
// => 8 consecutive lanes read one 128B row contiguously (coalesced),
//    and all 8 gather loads are independent/in-flight (deep MLP).
__global__ __launch_bounds__(256) void contrast_main(
    const float* __restrict__ features,
    const int* __restrict__ labels,
    const int* __restrict__ nbr,
    float* __restrict__ ws)   // ws[0]=loss sum, ws[1]=valid count
{
    const int lane = threadIdx.x & 63;
    const int wave = threadIdx.x >> 6;
    const int p0 = blockIdx.x * 16 + wave * 4;   // 4 points per wave; 12500*16 == 200000 exactly

    const int m = lane >> 3;    // group (row within octet)
    const int c = lane & 7;     // 16B chunk within row

    // row t = lane: neighbor slot p0*16 + lane (coalesced idx load)
    const int idx_l  = nbr[p0 * KNBR + lane];
    const int labn_l = labels[idx_l];                  // scattered 4B, labels (800KB) is L2-resident
    const int labc_l = labels[p0 + (lane >> 4)];       // center label, lane 16*pt holds pt's

    // center features: cen[pt] = features[p0+pt][c*4 .. c*4+3]
    float4 cen[4];
    #pragma unroll
    for (int pt = 0; pt < 4; ++pt)
        cen[pt] = *(const float4*)(features + (size_t)(p0 + pt) * CDIM + c * 4);

    // fetch row indices for each gather instruction via cross-lane shuffle
    int ridx[8];
    #pragma unroll
    for (int j = 0; j < 8; ++j)
        ridx[j] = __shfl(idx_l, 8 * j + m);

    // 8 independent coalesced row gathers, all in flight
    float4 v[8];
    #pragma unroll
    for (int j = 0; j < 8; ++j)
        v[j] = *(const float4*)(features + (size_t)ridx[j] * CDIM + c * 4);

    // per-row distance: partial dot in-lane, then reduce over the 8 chunk lanes
    float dj[8];
    #pragma unroll
    for (int j = 0; j < 8; ++j) {
        float4 ce = cen[j >> 1];           // rows 8j..8j+7 all belong to point j/2
        float dx = ce.x - v[j].x;
        float dy = ce.y - v[j].y;
        float dz = ce.z - v[j].z;
        float dw = ce.w - v[j].w;
        float d2 = dx * dx + dy * dy + dz * dz + dw * dw;
        d2 += __shfl_xor(d2, 1);
        d2 += __shfl_xor(d2, 2);
        d2 += __shfl_xor(d2, 4);
        dj[j] = sqrtf(d2 + EPSV);          // dist of row 8j+m, replicated over chunk lanes
    }

    // softmax per point: point pt's 16 rows live in dj[2pt] (rows 16pt+m) and dj[2pt+1] (16pt+8+m)
    float loss_acc = 0.f, valid_acc = 0.f;
    #pragma unroll
    for (int pt = 0; pt < 4; ++pt) {
        float a = dj[2 * pt];
        float b = dj[2 * pt + 1];
        float mn = fminf(a, b);
        mn = fminf(mn, __shfl_xor(mn, 8));
        mn = fminf(mn, __shfl_xor(mn, 16));
        mn = fminf(mn, __shfl_xor(mn, 32));
        const float ea = expf((mn - a) / TEMP);
        const float eb = expf((mn - b) / TEMP);

        const int la = __shfl(labn_l, 16 * pt + m);
        const int lb = __shfl(labn_l, 16 * pt + 8 + m);
        const int lc = __shfl(labc_l, 16 * pt);

        float pos_s = (la == lc ? ea : 0.f) + (lb == lc ? eb : 0.f);
        float neg_s = ea + eb;
        float cnt_s = (la == lc ? 1.f : 0.f) + (lb == lc ? 1.f : 0.f);
        #pragma unroll
        for (int off = 8; off <= 32; off <<= 1) {
            pos_s += __shfl_xor(pos_s, off);
            neg_s += __shfl_xor(neg_s, off);
            cnt_s += __shfl_xor(cnt_s, off);
        }

        if (lane == pt) {   // one lane per point accumulates
            const int icnt = (int)(cnt_s + 0.5f);
            if (icnt > 0 && icnt < KNBR) {
                loss_acc += -logf(pos_s / neg_s + EPSV);
                valid_acc += 1.f;
            }
        }
    }

    __shared__ float s_loss;
    __shared__ float s_cnt;
    if (threadIdx.x == 0) { s_loss = 0.f; s_cnt = 0.f; }
    __syncthreads();
    if (lane < 4) {
        atomicAdd(&s_loss, loss_acc);
        atomicAdd(&s_cnt, valid_acc);
    }
    __syncthreads();
    if (threadIdx.x == 0) {
        atomicAdd(&ws[0], s_loss);
        atomicAdd(&ws[1], s_cnt);
    }
}

__global__ void contrast_finalize(const float* __restrict__ ws,
                                  float* __restrict__ out)
{
    const float denom = fmaxf(ws[1], 1.f);
    out[0] = ws[0] / denom * WEIGHT;
}

extern "C" void kernel_launch(void* const* d_in, const int* in_sizes, int n_in,
                              void* d_out, int out_size, void* d_ws, size_t ws_size,
                              hipStream_t stream) {
    const float* features = (const float*)d_in[0];
    const int* labels     = (const int*)d_in[1];
    const int* nbr        = (const int*)d_in[2];
    float* out = (float*)d_out;
    float* ws  = (float*)d_ws;

    hipMemsetAsync(ws, 0, 2 * sizeof(float), stream);

    const int blocks = NPTS / 16;   // 12500, exact
    contrast_main<<<blocks, 256, 0, stream>>>(features, labels, nbr, ws);
    contrast_finalize<<<1, 1, 0, stream>>>(ws, out);
}

// Round 3
// 263.200 us; speedup vs baseline: 1.5381x; 1.5381x over previous
//
#include <hip/hip_runtime.h>
#include <math.h>

#define NPTS 200000
#define KNBR 16
#define CDIM 32
#define TEMP 0.1f
#define WEIGHT 0.1f
#define EPSV 1e-8f

#define TBL_OFF 256                       // bf16 table offset (bytes) inside ws
#define TBL_BYTES (NPTS * CDIM * 2)       // 12,800,000

static __device__ __forceinline__ unsigned f2bf(float x) {
    unsigned u = __float_as_uint(x);
    unsigned r = (u >> 16) & 1u;          // round-to-nearest-even
    u += 0x7fffu + r;
    return u >> 16;
}

// features f32 [N*C] -> packed bf16 table. 8 elements per thread.
__global__ __launch_bounds__(256) void to_bf16(const float* __restrict__ f,
                                               unsigned* __restrict__ o) {
    const int i = blockIdx.x * 256 + threadIdx.x;   // 800000 threads, exact
    const float4 a = ((const float4*)f)[2 * i];
    const float4 b = ((const float4*)f)[2 * i + 1];
    uint4 o4;
    o4.x = f2bf(a.x) | (f2bf(a.y) << 16);
    o4.y = f2bf(a.z) | (f2bf(a.w) << 16);
    o4.z = f2bf(b.x) | (f2bf(b.y) << 16);
    o4.w = f2bf(b.z) | (f2bf(b.w) << 16);
    ((uint4*)o)[i] = o4;
}

// One wave handles 8 points = 128 neighbor rows (64B bf16 rows).
// Gather j (0..7): lane L reads row 16j + (L>>2), 16B chunk (L&3).
// 4 consecutive lanes cover one 64B row; 8 gathers in flight.
__global__ __launch_bounds__(256) void contrast_bf16(
    const unsigned short* __restrict__ feat16,
    const int* __restrict__ labels,
    const int* __restrict__ nbr,
    float* __restrict__ ws) {
    const int lane = threadIdx.x & 63;
    const int wave = threadIdx.x >> 6;
    const int p0 = blockIdx.x * 32 + wave * 8;   // 6250 blocks * 32 = 200000 exact
    const int r = lane >> 2;                     // neighbor index 0..15
    const int c = lane & 3;                      // feature chunk: 8c..8c+7

    const int base = p0 * KNBR;                  // 128 rows: base..base+127
    const int idxA = nbr[base + lane];
    const int idxB = nbr[base + 64 + lane];
    const int labnA = labels[idxA];              // scattered 4B, 800KB table (L2-resident)
    const int labnB = labels[idxB];
    const int labc_l = labels[p0 + (lane & 7)];  // lane j<8 holds center label of point j

    int ridx[8];
    #pragma unroll
    for (int j = 0; j < 8; ++j) {
        const int rowmod = (j & 3) * 16 + r;     // (16j+r) & 63
        ridx[j] = (j < 4) ? __shfl(idxA, rowmod) : __shfl(idxB, rowmod);
    }

    uint4 v[8];
    #pragma unroll
    for (int j = 0; j < 8; ++j)
        v[j] = *(const uint4*)(feat16 + (size_t)ridx[j] * CDIM + 8 * c);

    uint4 cen[8];
    #pragma unroll
    for (int j = 0; j < 8; ++j)
        cen[j] = *(const uint4*)(feat16 + (size_t)(p0 + j) * CDIM + 8 * c);

    float dj[8];
    #pragma unroll
    for (int j = 0; j < 8; ++j) {
        const unsigned* pv = (const unsigned*)&v[j];
        const unsigned* pc = (const unsigned*)&cen[j];
        float d2 = 0.f;
        #pragma unroll
        for (int q = 0; q < 4; ++q) {
            const float nlo = __uint_as_float(pv[q] << 16);
            const float nhi = __uint_as_float(pv[q] & 0xffff0000u);
            const float clo = __uint_as_float(pc[q] << 16);
            const float chi = __uint_as_float(pc[q] & 0xffff0000u);
            const float dlo = clo - nlo;
            const float dhi = chi - nhi;
            d2 += dlo * dlo + dhi * dhi;
        }
        d2 += __shfl_xor(d2, 1);
        d2 += __shfl_xor(d2, 2);                 // full dist^2 of row 16j+r, x4 replicated
        dj[j] = sqrtf(d2 + EPSV);
    }

    float loss_acc = 0.f, valid_acc = 0.f;
    #pragma unroll
    for (int j = 0; j < 8; ++j) {
        const float d = dj[j];
        float mn = d;
        mn = fminf(mn, __shfl_xor(mn, 4));
        mn = fminf(mn, __shfl_xor(mn, 8));
        mn = fminf(mn, __shfl_xor(mn, 16));
        mn = fminf(mn, __shfl_xor(mn, 32));
        const float e = expf((mn - d) * (1.0f / TEMP));

        const int rowmod = (j & 3) * 16 + r;
        const int ln = (j < 4) ? __shfl(labnA, rowmod) : __shfl(labnB, rowmod);
        const int lc = __shfl(labc_l, j);
        const bool pos = (ln == lc);

        float pos_s = pos ? e : 0.f;
        float neg_s = e;
        float cnt_s = pos ? 1.f : 0.f;
        #pragma unroll
        for (int off = 4; off <= 32; off <<= 1) {   // sum over the 16 r-groups (c fixed)
            pos_s += __shfl_xor(pos_s, off);
            neg_s += __shfl_xor(neg_s, off);
            cnt_s += __shfl_xor(cnt_s, off);
        }
        if (lane == j) {
            const int icnt = (int)(cnt_s + 0.5f);
            if (icnt > 0 && icnt < KNBR) {
                loss_acc += -logf(pos_s / neg_s + EPSV);
                valid_acc += 1.f;
            }
        }
    }

    // lanes 0..7 hold per-point contributions; reduce to lane 0
    #pragma unroll
    for (int off = 1; off < 8; off <<= 1) {
        loss_acc += __shfl_xor(loss_acc, off);
        valid_acc += __shfl_xor(valid_acc, off);
    }

    __shared__ float s_loss, s_cnt;
    if (threadIdx.x == 0) { s_loss = 0.f; s_cnt = 0.f; }
    __syncthreads();
    if (lane == 0) {
        atomicAdd(&s_loss, loss_acc);
        atomicAdd(&s_cnt, valid_acc);
    }
    __syncthreads();
    if (threadIdx.x == 0) {
        atomicAdd(&ws[0], s_loss);
        atomicAdd(&ws[1], s_cnt);
    }
}

// -------- fp32 fallback (R2 path) if ws is too small for the bf16 table ----
__global__ __launch_bounds__(256) void contrast_fp32(
    const float* __restrict__ features,
    const int* __restrict__ labels,
    const int* __restrict__ nbr,
    float* __restrict__ ws) {
    const int lane = threadIdx.x & 63;
    const int wave = threadIdx.x >> 6;
    const int p0 = blockIdx.x * 16 + wave * 4;
    const int m = lane >> 3;
    const int c = lane & 7;

    const int idx_l = nbr[p0 * KNBR + lane];
    const int labn_l = labels[idx_l];
    const int labc_l = labels[p0 + (lane >> 4)];

    float4 cen[4];
    #pragma unroll
    for (int pt = 0; pt < 4; ++pt)
        cen[pt] = *(const float4*)(features + (size_t)(p0 + pt) * CDIM + c * 4);

    int ridx[8];
    #pragma unroll
    for (int j = 0; j < 8; ++j) ridx[j] = __shfl(idx_l, 8 * j + m);

    float4 v[8];
    #pragma unroll
    for (int j = 0; j < 8; ++j)
        v[j] = *(const float4*)(features + (size_t)ridx[j] * CDIM + c * 4);

    float dj[8];
    #pragma unroll
    for (int j = 0; j < 8; ++j) {
        float4 ce = cen[j >> 1];
        float dx = ce.x - v[j].x, dy = ce.y - v[j].y;
        float dz = ce.z - v[j].z, dw = ce.w - v[j].w;
        float d2 = dx * dx + dy * dy + dz * dz + dw * dw;
        d2 += __shfl_xor(d2, 1);
        d2 += __shfl_xor(d2, 2);
        d2 += __shfl_xor(d2, 4);
        dj[j] = sqrtf(d2 + EPSV);
    }

    float loss_acc = 0.f, valid_acc = 0.f;
    #pragma unroll
    for (int pt = 0; pt < 4; ++pt) {
        float a = dj[2 * pt], b = dj[2 * pt + 1];
        float mn = fminf(a, b);
        mn = fminf(mn, __shfl_xor(mn, 8));
        mn = fminf(mn, __shfl_xor(mn, 16));
        mn = fminf(mn, __shfl_xor(mn, 32));
        const float ea = expf((mn - a) / TEMP);
        const float eb = expf((mn - b) / TEMP);
        const int la = __shfl(labn_l, 16 * pt + m);
        const int lb = __shfl(labn_l, 16 * pt + 8 + m);
        const int lc = __shfl(labc_l, 16 * pt);
        float pos_s = (la == lc ? ea : 0.f) + (lb == lc ? eb : 0.f);
        float neg_s = ea + eb;
        float cnt_s = (la == lc ? 1.f : 0.f) + (lb == lc ? 1.f : 0.f);
        #pragma unroll
        for (int off = 8; off <= 32; off <<= 1) {
            pos_s += __shfl_xor(pos_s, off);
            neg_s += __shfl_xor(neg_s, off);
            cnt_s += __shfl_xor(cnt_s, off);
        }
        if (lane == pt) {
            const int icnt = (int)(cnt_s + 0.5f);
            if (icnt > 0 && icnt < KNBR) {
                loss_acc += -logf(pos_s / neg_s + EPSV);
                valid_acc += 1.f;
            }
        }
    }

    __shared__ float s_loss, s_cnt;
    if (threadIdx.x == 0) { s_loss = 0.f; s_cnt = 0.f; }
    __syncthreads();
    if (lane < 4) {
        atomicAdd(&s_loss, loss_acc);
        atomicAdd(&s_cnt, valid_acc);
    }
    __syncthreads();
    if (threadIdx.x == 0) {
        atomicAdd(&ws[0], s_loss);
        atomicAdd(&ws[1], s_cnt);
    }
}

__global__ void contrast_finalize(const float* __restrict__ ws,
                                  float* __restrict__ out) {
    const float denom = fmaxf(ws[1], 1.f);
    out[0] = ws[0] / denom * WEIGHT;
}

extern "C" void kernel_launch(void* const* d_in, const int* in_sizes, int n_in,
                              void* d_out, int out_size, void* d_ws, size_t ws_size,
                              hipStream_t stream) {
    const float* features = (const float*)d_in[0];
    const int* labels     = (const int*)d_in[1];
    const int* nbr        = (const int*)d_in[2];
    float* out = (float*)d_out;
    float* ws  = (float*)d_ws;

    hipMemsetAsync(ws, 0, 2 * sizeof(float), stream);

    if (ws_size >= (size_t)(TBL_OFF + TBL_BYTES)) {
        unsigned short* tbl = (unsigned short*)((char*)d_ws + TBL_OFF);
        to_bf16<<<NPTS * CDIM / 8 / 256, 256, 0, stream>>>(features, (unsigned*)tbl);
        contrast_bf16<<<NPTS / 32, 256, 0, stream>>>(tbl, labels, nbr, ws);
    } else {
        contrast_fp32<<<NPTS / 16, 256, 0, stream>>>(features, labels, nbr, ws);
    }
    contrast_finalize<<<1, 1, 0, stream>>>(ws, out);
}

// Round 4
// 180.409 us; speedup vs baseline: 2.2440x; 1.4589x over previous
//
#include <hip/hip_runtime.h>
#include <math.h>

#define NPTS 200000
#define KNBR 16
#define CDIM 32
#define TEMP 0.1f
#define WEIGHT 0.1f
#define EPSV 1e-8f

#define TBL_OFF 256
#define TBL_BYTES (NPTS * CDIM)           // fp8: 6,400,000 bytes

typedef float v2f __attribute__((ext_vector_type(2)));

// ---------------- pre-pass: f32 features -> packed fp8 e4m3 table ----------
// thread i handles 8 consecutive floats -> 8 fp8 (uint2)
__global__ __launch_bounds__(256) void to_fp8(const float* __restrict__ f,
                                              unsigned* __restrict__ o) {
    const int i = blockIdx.x * 256 + threadIdx.x;   // 800000 threads exact
    const float4 a = ((const float4*)f)[2 * i];
    const float4 b = ((const float4*)f)[2 * i + 1];
    int w0 = 0, w1 = 0;
    w0 = __builtin_amdgcn_cvt_pk_fp8_f32(a.x, a.y, w0, false);
    w0 = __builtin_amdgcn_cvt_pk_fp8_f32(a.z, a.w, w0, true);
    w1 = __builtin_amdgcn_cvt_pk_fp8_f32(b.x, b.y, w1, false);
    w1 = __builtin_amdgcn_cvt_pk_fp8_f32(b.z, b.w, w1, true);
    ((uint2*)o)[i] = make_uint2((unsigned)w0, (unsigned)w1);
}

// ---------------- main: one wave = 16 points = 256 neighbor rows -----------
// fp8 row = 32B = 2 lanes x 16B. Gather j (0..7): lane L reads row 32j+(L>>1),
// 16B chunk (L&1). 8 gather instructions x 32 rows each, all in flight.
__global__ __launch_bounds__(256) void contrast_fp8(
    const unsigned char* __restrict__ tbl,
    const int* __restrict__ labels,
    const int* __restrict__ nbr,
    float* __restrict__ ws) {
    const int lane = threadIdx.x & 63;
    const int wave = threadIdx.x >> 6;
    const int p0 = blockIdx.x * 64 + wave * 16;   // 3125 blocks * 64 = 200000
    const int h = lane >> 1;                      // half-row id 0..31
    const int c = lane & 1;                       // 16B chunk in row

    // 256 neighbor indices per wave, coalesced
    const int base = p0 * KNBR;
    int idxq[4], labnq[4];
    #pragma unroll
    for (int t = 0; t < 4; ++t) idxq[t] = nbr[base + t * 64 + lane];
    #pragma unroll
    for (int t = 0; t < 4; ++t) labnq[t] = labels[idxq[t]];  // 800KB table, L2-hot
    const int labc_l = labels[p0 + (lane & 15)];             // lane q<16: label of point q

    // row r_j = 32j + h ; source reg t=j>>1, src lane offset 32*(j&1)+h
    int ridx[8];
    #pragma unroll
    for (int j = 0; j < 8; ++j)
        ridx[j] = __shfl(idxq[j >> 1], 32 * (j & 1) + h);

    // gathers: 8 independent, in flight
    uint4 v[8];
    #pragma unroll
    for (int j = 0; j < 8; ++j)
        v[j] = *(const uint4*)(tbl + (size_t)ridx[j] * CDIM + 16 * c);

    // centers: point of row r_j is 2j + (h>>4)
    uint4 cen[8];
    #pragma unroll
    for (int j = 0; j < 8; ++j)
        cen[j] = *(const uint4*)(tbl + (size_t)(p0 + 2 * j + (h >> 4)) * CDIM + 16 * c);

    // distances
    float dj[8];
    #pragma unroll
    for (int j = 0; j < 8; ++j) {
        const unsigned* pv = (const unsigned*)&v[j];
        const unsigned* pc = (const unsigned*)&cen[j];
        float d2 = 0.f;
        #pragma unroll
        for (int q = 0; q < 4; ++q) {
            v2f nl = __builtin_amdgcn_cvt_pk_f32_fp8((int)pv[q], false);
            v2f nh = __builtin_amdgcn_cvt_pk_f32_fp8((int)pv[q], true);
            v2f cl = __builtin_amdgcn_cvt_pk_f32_fp8((int)pc[q], false);
            v2f ch = __builtin_amdgcn_cvt_pk_f32_fp8((int)pc[q], true);
            float d0 = cl.x - nl.x, d1 = cl.y - nl.y;
            float d2a = ch.x - nh.x, d3 = ch.y - nh.y;
            d2 += d0 * d0 + d1 * d1 + d2a * d2a + d3 * d3;
        }
        d2 += __shfl_xor(d2, 1);              // combine the 2 chunk lanes
        dj[j] = sqrtf(d2 + EPSV);
    }

    // per-point softmax: point 2j+g (g=h>>4) rows live at lanes 32g + {2k+c},
    // k = h&15. Reduce over k-bits = shfl_xor offsets {2,4,8,16}.
    float loss_acc = 0.f, valid_acc = 0.f;
    #pragma unroll
    for (int j = 0; j < 8; ++j) {
        const float d = dj[j];
        float mn = d;
        mn = fminf(mn, __shfl_xor(mn, 2));
        mn = fminf(mn, __shfl_xor(mn, 4));
        mn = fminf(mn, __shfl_xor(mn, 8));
        mn = fminf(mn, __shfl_xor(mn, 16));
        const float e = expf((mn - d) * (1.0f / TEMP));

        const int ln = __shfl(labnq[j >> 1], 32 * (j & 1) + h);
        const int lc = __shfl(labc_l, 2 * j + (h >> 4));
        const bool pos = (ln == lc);

        float pos_s = pos ? e : 0.f;
        float neg_s = e;
        float cnt_s = pos ? 1.f : 0.f;
        #pragma unroll
        for (int off = 2; off <= 16; off <<= 1) {
            pos_s += __shfl_xor(pos_s, off);
            neg_s += __shfl_xor(neg_s, off);
            cnt_s += __shfl_xor(cnt_s, off);
        }
        // accumulator lanes: even point 2j -> lane 2j (g=0 region),
        // odd point 2j+1 -> lane 33+2j (g=1 region)
        if (lane == 2 * j || lane == 33 + 2 * j) {
            const int icnt = (int)(cnt_s + 0.5f);
            if (icnt > 0 && icnt < KNBR) {
                loss_acc += -logf(pos_s / neg_s + EPSV);
                valid_acc += 1.f;
            }
        }
    }

    // full-wave sum (non-accumulator lanes hold 0)
    #pragma unroll
    for (int off = 1; off <= 32; off <<= 1) {
        loss_acc += __shfl_xor(loss_acc, off);
        valid_acc += __shfl_xor(valid_acc, off);
    }

    __shared__ float s_loss, s_cnt;
    if (threadIdx.x == 0) { s_loss = 0.f; s_cnt = 0.f; }
    __syncthreads();
    if (lane == 0) {
        atomicAdd(&s_loss, loss_acc);
        atomicAdd(&s_cnt, valid_acc);
    }
    __syncthreads();
    if (threadIdx.x == 0) {
        atomicAdd(&ws[0], s_loss);
        atomicAdd(&ws[1], s_cnt);
    }
}

// ---------------- fp32 fallback (only if ws too small; not expected) -------
__global__ __launch_bounds__(256) void contrast_fp32(
    const float* __restrict__ features,
    const int* __restrict__ labels,
    const int* __restrict__ nbr,
    float* __restrict__ ws) {
    const int lane = threadIdx.x & 63;
    const int wave = threadIdx.x >> 6;
    const int p0 = blockIdx.x * 16 + wave * 4;
    const int m = lane >> 3;
    const int c = lane & 7;

    const int idx_l = nbr[p0 * KNBR + lane];
    const int labn_l = labels[idx_l];
    const int labc_l = labels[p0 + (lane >> 4)];

    float4 cen[4];
    #pragma unroll
    for (int pt = 0; pt < 4; ++pt)
        cen[pt] = *(const float4*)(features + (size_t)(p0 + pt) * CDIM + c * 4);

    int ridx[8];
    #pragma unroll
    for (int j = 0; j < 8; ++j) ridx[j] = __shfl(idx_l, 8 * j + m);

    float4 v[8];
    #pragma unroll
    for (int j = 0; j < 8; ++j)
        v[j] = *(const float4*)(features + (size_t)ridx[j] * CDIM + c * 4);

    float dj[8];
    #pragma unroll
    for (int j = 0; j < 8; ++j) {
        float4 ce = cen[j >> 1];
        float dx = ce.x - v[j].x, dy = ce.y - v[j].y;
        float dz = ce.z - v[j].z, dw = ce.w - v[j].w;
        float d2 = dx * dx + dy * dy + dz * dz + dw * dw;
        d2 += __shfl_xor(d2, 1);
        d2 += __shfl_xor(d2, 2);
        d2 += __shfl_xor(d2, 4);
        dj[j] = sqrtf(d2 + EPSV);
    }

    float loss_acc = 0.f, valid_acc = 0.f;
    #pragma unroll
    for (int pt = 0; pt < 4; ++pt) {
        float a = dj[2 * pt], b = dj[2 * pt + 1];
        float mn = fminf(a, b);
        mn = fminf(mn, __shfl_xor(mn, 8));
        mn = fminf(mn, __shfl_xor(mn, 16));
        mn = fminf(mn, __shfl_xor(mn, 32));
        const float ea = expf((mn - a) / TEMP);
        const float eb = expf((mn - b) / TEMP);
        const int la = __shfl(labn_l, 16 * pt + m);
        const int lb = __shfl(labn_l, 16 * pt + 8 + m);
        const int lc = __shfl(labc_l, 16 * pt);
        float pos_s = (la == lc ? ea : 0.f) + (lb == lc ? eb : 0.f);
        float neg_s = ea + eb;
        float cnt_s = (la == lc ? 1.f : 0.f) + (lb == lc ? 1.f : 0.f);
        #pragma unroll
        for (int off = 8; off <= 32; off <<= 1) {
            pos_s += __shfl_xor(pos_s, off);
            neg_s += __shfl_xor(neg_s, off);
            cnt_s += __shfl_xor(cnt_s, off);
        }
        if (lane == pt) {
            const int icnt = (int)(cnt_s + 0.5f);
            if (icnt > 0 && icnt < KNBR) {
                loss_acc += -logf(pos_s / neg_s + EPSV);
                valid_acc += 1.f;
            }
        }
    }

    __shared__ float s_loss, s_cnt;
    if (threadIdx.x == 0) { s_loss = 0.f; s_cnt = 0.f; }
    __syncthreads();
    if (lane < 4) {
        atomicAdd(&s_loss, loss_acc);
        atomicAdd(&s_cnt, valid_acc);
    }
    __syncthreads();
    if (threadIdx.x == 0) {
        atomicAdd(&ws[0], s_loss);
        atomicAdd(&ws[1], s_cnt);
    }
}

__global__ void contrast_finalize(const float* __restrict__ ws,
                                  float* __restrict__ out) {
    const float denom = fmaxf(ws[1], 1.f);
    out[0] = ws[0] / denom * WEIGHT;
}

extern "C" void kernel_launch(void* const* d_in, const int* in_sizes, int n_in,
                              void* d_out, int out_size, void* d_ws, size_t ws_size,
                              hipStream_t stream) {
    const float* features = (const float*)d_in[0];
    const int* labels     = (const int*)d_in[1];
    const int* nbr        = (const int*)d_in[2];
    float* out = (float*)d_out;
    float* ws  = (float*)d_ws;

    hipMemsetAsync(ws, 0, 2 * sizeof(float), stream);

    if (ws_size >= (size_t)(TBL_OFF + TBL_BYTES)) {
        unsigned char* tbl = (unsigned char*)d_ws + TBL_OFF;
        to_fp8<<<NPTS * CDIM / 8 / 256, 256, 0, stream>>>(features, (unsigned*)tbl);
        contrast_fp8<<<NPTS / 64, 256, 0, stream>>>(tbl, labels, nbr, ws);
    } else {
        contrast_fp32<<<NPTS / 16, 256, 0, stream>>>(features, labels, nbr, ws);
    }
    contrast_finalize<<<1, 1, 0, stream>>>(ws, out);
}